// Round 16
// baseline (2622.410 us; speedup 1.0000x reference)
//
#include <hip/hip_runtime.h>
#include <hip/hip_bf16.h>
#include <stdint.h>

#define HD   512   // hidden dim H
#define ID   128   // input dim I
#define NCLS 100   // num classes
#define TT   512   // sequence length T
#define BB   128   // batch B
#define NEMB 101   // NC + 1 embedding rows
#define NGRP 16    // independent batch groups
#define GWG  16    // workgroups per group (dataflow clique)
#define RPG  8     // batch rows per group
#define COLS 32    // hidden cols per WG (GWG*COLS == HD)
#define THR  1024  // threads per recurrence WG (16 waves, 4 waves/SIMD)
#define CPAD 520   // LDS C row stride (mult of 4 -> float4-aligned; skews banks)
#define PST2 9     // partials stride in float2 units (odd -> bank-skewed)

// workspace layout (bytes)
#define WS_FLAG 0
#define WS_G    65536                  // float G[101][2048]   (808 KB)
#define WS_CT0  (1u * 1024 * 1024)     // u64 Ct0[128][512]    (512 KB) tagged C
#define WS_CT1  (WS_CT0 + 524288)      // u64 Ct1[128][512]    (512 KB)
#define WS_HFB  (WS_CT1 + 524288)      // float Hfb[128][512]  (256 KB)

using bf16 = __hip_bfloat16;
using u64  = unsigned long long;

__device__ __forceinline__ float b2f(bf16 v) { return __bfloat162float(v); }
__device__ __forceinline__ float sigf(float x) { return 1.0f / (1.0f + expf(-x)); }

// IF-scope (sc1) tagged-word accessors — same __hip_atomic family proven
// r6-r15, widened to 8 bytes (single global_load/store_dwordx2 sc1).
// Tag and payload travel in ONE atomic word: the data IS the barrier.
__device__ __forceinline__ u64 cld64(const u64* p) {
    return __hip_atomic_load(p, __ATOMIC_RELAXED, __HIP_MEMORY_SCOPE_AGENT);
}
__device__ __forceinline__ void cst64(u64* p, u64 v) {
    __hip_atomic_store(p, v, __ATOMIC_RELAXED, __HIP_MEMORY_SCOPE_AGENT);
}
__device__ __forceinline__ u64 packCT(float v, unsigned t) {
    return ((u64)t << 32) | (u64)__float_as_uint(v);
}

template <bool BF>
__device__ __forceinline__ float ldv(const void* p, int i) {
    if constexpr (BF) return b2f(((const bf16*)p)[i]);
    else              return ((const float*)p)[i];
}

// ---------------------------------------------------------------------------
// Dtype sniffer. emb row 0 is exactly 0.0 by construction: bytes [256,512)
// are zero iff f32 (row 0) and nonzero iff bf16 (row 1).
// ---------------------------------------------------------------------------
__global__ void init_k(const uint32_t* __restrict__ emb_raw, int* __restrict__ flag) {
    if (threadIdx.x == 0) {
        uint32_t acc = 0;
        for (int i = 64; i < 128; ++i) acc |= emb_raw[i];
        *flag = (acc == 0u) ? 0 : 1;
    }
}

// ---------------------------------------------------------------------------
// G[c][j]: input-side gate pre-activations per class. j = q*512 + col,
// q in {0:f, 1:i, 2:o, 3:ctilde}; ctilde quarter pre-sigmoided.
// ---------------------------------------------------------------------------
template <bool BF>
__global__ void build_G(const int* __restrict__ flag,
                        const void* __restrict__ emb,
                        const void* __restrict__ Wfx, const void* __restrict__ Wix,
                        const void* __restrict__ Wox, const void* __restrict__ Wcx,
                        const void* __restrict__ bfv, const void* __restrict__ biv,
                        const void* __restrict__ bov, const void* __restrict__ bcv,
                        float* __restrict__ G) {
    if (*flag != (BF ? 1 : 0)) return;
    const int c   = blockIdx.x;
    const int j   = blockIdx.y * 256 + threadIdx.x;
    const int q   = j >> 9;
    const int col = j & 511;
    const void* W  = (q == 0) ? Wfx : (q == 1) ? Wix : (q == 2) ? Wox : Wcx;
    const void* bv = (q == 0) ? bfv : (q == 1) ? biv : (q == 2) ? bov : bcv;
    float acc = ldv<BF>(bv, col);
    for (int i = 0; i < ID; ++i)
        acc += ldv<BF>(emb, c * ID + i) * ldv<BF>(W, i * HD + col);
    if (q == 3) acc = sigf(acc);
    G[c * 2048 + j] = acc;
}

// ---------------------------------------------------------------------------
// Batch-split recurrence with TAGGED DATAFLOW exchange (r16) — no barriers.
// Each C element is a u64 (tag<<32 | float bits), double-buffered. Step t:
// consumers poll-load buf[t&1] until tag == t (one RTT; the 8B atomic makes
// tag/payload inseparable); producers store (C(t+1), t+1) to buf[(t+1)&1].
// Lap safety: a WG can write tag t+2 over a buffer only after observing ALL
// t+1 tags, which requires every WG consumed step t — the double buffer +
// monotone tags encode the barrier. '== t' matching also makes 0xAA ws
// poison (tag 0xAAAAAAAA) harmless. r13's counter-barrier chain
// (store-drain -> RMW -> poll -> release, ~2us) becomes one store + one
// poll (~0.8us), and per-step __syncthreads drops 4 -> 2.
// Epilogue: o-gate uses C(T-1) — already in LDS Cs from the final stage
// (r15's verified pre-update-C fix, absmax 0.125 -> 0.03125).
// ---------------------------------------------------------------------------
template <bool BF>
__global__ __launch_bounds__(THR, 1) void recur_bs(
    const int* __restrict__ flag, const int* __restrict__ x,
    const float* __restrict__ G,
    const void* __restrict__ Wfc, const void* __restrict__ Wic,
    const void* __restrict__ Woc,
    u64* __restrict__ Ct0, u64* __restrict__ Ct1,
    float* __restrict__ Hfb)
{
    if (*flag != (BF ? 1 : 0)) return;

    __shared__ __align__(16) float Cs[RPG * CPAD];     // 16.6 KB
    __shared__ __align__(8)  float2 part2[THR * PST2]; // 73.7 KB
    __shared__ int   idx[RPG * TT];                    // 16 KB
    __shared__ int   lz[RPG];

    const int blk   = blockIdx.x;
    const int grp   = blk >> 4;           // 0..15
    const int rank  = blk & 15;           // 0..15
    const int r0    = grp * RPG;
    const int h0    = rank * COLS;
    const int tid   = threadIdx.x;
    const int col   = tid & 31;
    const int chunk = tid >> 5;           // 0..31 (16 h' each)

    // ---- stage x rows (4096 ints, flat-contiguous), find group start ----
    #pragma unroll
    for (int k = 0; k < 4; ++k)
        idx[tid + 1024 * k] = x[r0 * TT + tid + 1024 * k];
    if (tid < RPG) lz[tid] = -1;
    __syncthreads();
    if (tid < TT)
        #pragma unroll
        for (int r = 0; r < RPG; ++r)
            if (idx[r * TT + tid] == 0) atomicMax(&lz[r], tid);
    __syncthreads();
    int t0 = TT;
    #pragma unroll
    for (int r = 0; r < RPG; ++r) t0 = min(t0, lz[r] + 1);
    // t0 is group-uniform: every WG computes it from the same 8 rows.

    // ---- 32 pinned register weights: BOTH gates, own col, own 16-h' chunk
    float wf[16], wi[16];
    {
        #pragma unroll
        for (int k = 0; k < 16; ++k) {
            wf[k] = ldv<BF>(Wfc, (chunk * 16 + k) * HD + h0 + col);
            wi[k] = ldv<BF>(Wic, (chunk * 16 + k) * HD + h0 + col);
        }
        #pragma unroll
        for (int k = 0; k < 16; ++k)
            asm volatile("" : "+v"(wf[k]), "+v"(wi[k]));
    }

    const bool isUpd = (tid < COLS * RPG);
    const int uc = tid & 31, ur = tid >> 5;   // update thread's (col, row)
    const int erow = tid >> 7;                // stage: row 0..7
    const int eh4  = (tid & 127) * 4;         // stage: h' base (4 consecutive)

    // ---- init own slice of the step-t0 buffer: (0.0, tag=t0) ----
    // Consumers poll for tag==t0, so no init barrier is needed.
    {
        u64* bufI = (t0 & 1) ? Ct1 : Ct0;
        if (isUpd)
            cst64(&bufI[(r0 + ur) * HD + h0 + uc], packCT(0.0f, (unsigned)t0));
    }

    float Creg = 0.0f;                    // update threads' own C element

    for (int t = t0; t < TT; ++t) {
        const u64* cur = (t & 1) ? Ct1 : Ct0;
        u64*       nxt = (t & 1) ? Ct0 : Ct1;
        const unsigned tg = (unsigned)t;

        // ---- prefetch G gate operands for the update (overlaps the poll) --
        float gf = 0.f, gi = 0.f, sgc = 0.f;
        int cl = 1;
        if (isUpd) {
            cl = idx[ur * TT + t];
            const float* Gr = G + cl * 2048;
            gf  = Gr[h0 + uc];
            gi  = Gr[512 + h0 + uc];
            sgc = Gr[1536 + h0 + uc];
        }

        // ---- poll-stage C(t): 4 tagged words of row erow at h'=eh4 ----
        {
            const u64* cb = cur + (r0 + erow) * HD + eh4;
            u64 a0, a1, a2, a3;
            for (;;) {
                a0 = cld64(cb);
                a1 = cld64(cb + 1);
                a2 = cld64(cb + 2);
                a3 = cld64(cb + 3);
                if ((unsigned)(a0 >> 32) == tg && (unsigned)(a1 >> 32) == tg &&
                    (unsigned)(a2 >> 32) == tg && (unsigned)(a3 >> 32) == tg)
                    break;
            }
            float* cs = Cs + erow * CPAD + eh4;
            cs[0] = __uint_as_float((unsigned)a0);
            cs[1] = __uint_as_float((unsigned)a1);
            cs[2] = __uint_as_float((unsigned)a2);
            cs[3] = __uint_as_float((unsigned)a3);
        }
        __syncthreads();                       // S1: Cs ready (also fences part2)

        // ---- both-gate dot over 16 h' (2-way broadcast LDS reads) ----
        float accf[RPG], acci[RPG];
        #pragma unroll
        for (int r = 0; r < RPG; ++r) { accf[r] = 0.0f; acci[r] = 0.0f; }
        {
            const int cb4 = chunk * 4;    // float4 index of chunk base
            #pragma unroll
            for (int j = 0; j < 4; ++j) {
                const float f0 = wf[4*j], f1 = wf[4*j+1], f2 = wf[4*j+2], f3 = wf[4*j+3];
                const float i0 = wi[4*j], i1 = wi[4*j+1], i2 = wi[4*j+2], i3 = wi[4*j+3];
                #pragma unroll
                for (int r = 0; r < RPG; ++r) {
                    const float4 cv = reinterpret_cast<const float4*>(
                        Cs + r * CPAD)[cb4 + j];
                    accf[r] += f0*cv.x + f1*cv.y + f2*cv.z + f3*cv.w;
                    acci[r] += i0*cv.x + i1*cv.y + i2*cv.z + i3*cv.w;
                }
            }
        }
        {
            float2* pp = part2 + tid * PST2;
            #pragma unroll
            for (int r = 0; r < RPG; ++r)
                pp[r] = make_float2(accf[r], acci[r]);
        }
        __syncthreads();                       // S2: partials ready (fences Cs)

        // ---- update + tagged store; no barrier ----
        if (isUpd) {
            float df = 0.f, di = 0.f;
            #pragma unroll
            for (int ch = 0; ch < 32; ++ch) {
                const float2 v = part2[(ch * 32 + uc) * PST2 + ur];
                df += v.x;
                di += v.y;
            }
            float Cn = sgc * sigf(gi + di) + Creg * sigf(gf + df);
            Cn = (cl > 0) ? Cn : 0.0f;
            Creg = Cn;
            cst64(&nxt[(r0 + ur) * HD + h0 + uc], packCT(Cn, tg + 1u));
        }
    }

    // ---- o-gate + h once. o uses C(T-1) (pre-update at the final step) —
    // already in Cs from the loop's final stage (t=TT-1). If t0==TT the loop
    // never ran: then every row resets at T-1, Creg==0, h==0 regardless of o
    // (Cs garbage is finite — 0xAA poison is a tiny denormal, not NaN).
    {
        __syncthreads();                       // all dot reads of Cs done

        float ao[RPG];
        #pragma unroll
        for (int r = 0; r < RPG; ++r) ao[r] = 0.0f;
        #pragma unroll 4
        for (int k = 0; k < 16; ++k) {
            const int hp = chunk * 16 + k;
            const float wo = ldv<BF>(Woc, hp * HD + h0 + col);
            #pragma unroll
            for (int r = 0; r < RPG; ++r)
                ao[r] += wo * Cs[r * CPAD + hp];
        }
        {
            float2* pp = part2 + tid * PST2;
            #pragma unroll
            for (int r2 = 0; r2 < RPG / 2; ++r2)
                pp[r2] = make_float2(ao[2 * r2], ao[2 * r2 + 1]);
        }
        __syncthreads();
        if (isUpd) {
            float s = 0.f;
            #pragma unroll
            for (int ch = 0; ch < 32; ++ch) {
                const float2 v = part2[(ch * 32 + uc) * PST2 + (ur >> 1)];
                s += (ur & 1) ? v.y : v.x;
            }
            const int cl2 = idx[ur * TT + TT - 1];
            const float o = sigf(G[cl2 * 2048 + 1024 + h0 + uc] + s);
            Hfb[(r0 + ur) * HD + h0 + uc] = tanhf(Creg) * o;
        }
    }
}

// ---------------------------------------------------------------------------
// Projection + log_softmax, one WG per batch row.
// ---------------------------------------------------------------------------
template <bool BF>
__global__ __launch_bounds__(128) void proj(
    const int* __restrict__ flag, const float* __restrict__ Hfb,
    const void* __restrict__ Wph, const void* __restrict__ bp,
    void* __restrict__ out)
{
    if (*flag != (BF ? 1 : 0)) return;
    __shared__ __align__(16) float hv[HD];
    __shared__ float p_s[NCLS];
    __shared__ float lse_s;
    const int b   = blockIdx.x;
    const int tid = threadIdx.x;

    reinterpret_cast<float4*>(hv)[tid] =
        reinterpret_cast<const float4*>(Hfb + b * HD)[tid];
    __syncthreads();

    if (tid < NCLS) {
        float p = ldv<BF>(bp, tid);
        for (int h = 0; h < HD; ++h)
            p += hv[h] * ldv<BF>(Wph, h * NCLS + tid);
        p_s[tid] = p;
    }
    __syncthreads();
    if (tid == 0) {
        float m = -1e30f;
        for (int n = 0; n < NCLS; ++n) m = fmaxf(m, p_s[n]);
        float sum = 0.0f;
        for (int n = 0; n < NCLS; ++n) sum += expf(p_s[n] - m);
        lse_s = m + logf(sum);
    }
    __syncthreads();
    if (tid < NCLS) {
        const float v = p_s[tid] - lse_s;
        if constexpr (BF) ((bf16*)out)[b * NCLS + tid] = __float2bfloat16(v);
        else              ((float*)out)[b * NCLS + tid] = v;
    }
}

// ---------------------------------------------------------------------------
extern "C" void kernel_launch(void* const* d_in, const int* in_sizes, int n_in,
                              void* d_out, int out_size, void* d_ws, size_t ws_size,
                              hipStream_t stream) {
    const int*  x   = (const int*)d_in[0];
    const void* emb = d_in[1];
    const void* Wfx = d_in[2];
    const void* Wfc = d_in[3];
    const void* bfv = d_in[4];
    const void* Wix = d_in[5];
    const void* Wic = d_in[6];
    const void* biv = d_in[7];
    const void* Wox = d_in[8];
    const void* Woc = d_in[9];
    const void* bov = d_in[10];
    const void* Wcx = d_in[11];
    const void* bcv = d_in[12];
    const void* Wph = d_in[13];
    const void* bp  = d_in[14];

    int*   flag = (int*)((char*)d_ws + WS_FLAG);
    float* G    = (float*)((char*)d_ws + WS_G);
    u64*   Ct0  = (u64*)((char*)d_ws + WS_CT0);
    u64*   Ct1  = (u64*)((char*)d_ws + WS_CT1);
    float* Hfb  = (float*)((char*)d_ws + WS_HFB);

    init_k<<<1, 64, 0, stream>>>((const uint32_t*)emb, flag);

    build_G<false><<<dim3(NEMB, 8), 256, 0, stream>>>(flag, emb, Wfx, Wix, Wox, Wcx,
                                                      bfv, biv, bov, bcv, G);
    build_G<true ><<<dim3(NEMB, 8), 256, 0, stream>>>(flag, emb, Wfx, Wix, Wox, Wcx,
                                                      bfv, biv, bov, bcv, G);

    {
        void* args[] = {(void*)&flag, (void*)&x, (void*)&G,
                        (void*)&Wfc, (void*)&Wic, (void*)&Woc,
                        (void*)&Ct0, (void*)&Ct1, (void*)&Hfb};
        hipLaunchCooperativeKernel((const void*)recur_bs<false>, dim3(NGRP * GWG), dim3(THR),
                                   args, 0, stream);
        hipLaunchCooperativeKernel((const void*)recur_bs<true>, dim3(NGRP * GWG), dim3(THR),
                                   args, 0, stream);
    }

    proj<false><<<BB, 128, 0, stream>>>(flag, Hfb, Wph, bp, d_out);
    proj<true ><<<BB, 128, 0, stream>>>(flag, Hfb, Wph, bp, d_out);
}

// Round 17
// 2563.102 us; speedup vs baseline: 1.0231x; 1.0231x over previous
//
#include <hip/hip_runtime.h>
#include <hip/hip_bf16.h>
#include <stdint.h>

#define HD   512   // hidden dim H
#define ID   128   // input dim I
#define NCLS 100   // num classes
#define TT   512   // sequence length T
#define BB   128   // batch B
#define NEMB 101   // NC + 1 embedding rows
#define NGRP 16    // independent batch groups
#define GWG  16    // workgroups per group (sync clique)
#define RPG  8     // batch rows per group
#define COLS 32    // hidden cols per WG (GWG*COLS == HD)
#define THR  1024  // threads per recurrence WG (16 waves, 4 waves/SIMD)
#define CPAD 520   // LDS C row stride (mult of 4 -> float4-aligned; skews banks)
#define PST2 9     // partials stride in float2 units (odd -> bank-skewed)

// workspace layout (bytes)
#define WS_FLAG 0
#define WS_BAR  4096                   // u32 bars[12288] (48 KB): counters+slots
#define WS_G    65536                  // float G[101][2048]  (808 KB)
#define WS_C0   (1u * 1024 * 1024)     // float C0[128][512]  (256 KB)
#define WS_C1   (WS_C0 + 262144)       // float C1[128][512]  (256 KB)
#define WS_HFB  (WS_C1 + 262144)       // float Hfb[128][512] (256 KB)
#define NBARU   12288                  // u32s to zero
// bars u32 map: cntIF1=grp*64, cntIF2=grp*64+16, cntL2=grp*64+32,
//               xslots=2048+grp*16+r, cslots=4096+grp*512+r*32

using bf16 = __hip_bfloat16;
using u64  = unsigned long long;

__device__ __forceinline__ float b2f(bf16 v) { return __bfloat162float(v); }
__device__ __forceinline__ float sigf(float x) { return 1.0f / (1.0f + expf(-x)); }

// IF-scope (sc1) accessors — proven r6-r16.
__device__ __forceinline__ float cld(const float* p) {
    return __hip_atomic_load(p, __ATOMIC_RELAXED, __HIP_MEMORY_SCOPE_AGENT);
}
__device__ __forceinline__ void cst(float* p, float v) {
    __hip_atomic_store(p, v, __ATOMIC_RELAXED, __HIP_MEMORY_SCOPE_AGENT);
}
__device__ __forceinline__ unsigned cld_u(const unsigned* p) {
    return __hip_atomic_load(p, __ATOMIC_RELAXED, __HIP_MEMORY_SCOPE_AGENT);
}
__device__ __forceinline__ void cst_u(unsigned* p, unsigned v) {
    __hip_atomic_store(p, v, __ATOMIC_RELAXED, __HIP_MEMORY_SCOPE_AGENT);
}

template <bool BF>
__device__ __forceinline__ float ldv(const void* p, int i) {
    if constexpr (BF) return b2f(((const bf16*)p)[i]);
    else              return ((const float*)p)[i];
}

// ---------------------------------------------------------------------------
// IF-scope group barrier — r13's best-measured flavor (RMW + tight poll).
// Leading __syncthreads drains all waves' stores (vmcnt) before the arrive.
// ---------------------------------------------------------------------------
__device__ __forceinline__ void gbar_if(unsigned* cnt, unsigned* iter) {
    __syncthreads();
    if (threadIdx.x == 0) {
        __hip_atomic_fetch_add(cnt, 1u, __ATOMIC_RELAXED, __HIP_MEMORY_SCOPE_AGENT);
        const unsigned tgt = (*iter + 1u) * GWG;
        while (__hip_atomic_load(cnt, __ATOMIC_RELAXED, __HIP_MEMORY_SCOPE_AGENT) < tgt)
            ;
    }
    ++*iter;
    __syncthreads();
}

// ---------------------------------------------------------------------------
// Dtype sniffer + bars zeroing. emb row 0 is exactly 0.0 by construction:
// bytes [256,512) are zero iff f32 (row 0) and nonzero iff bf16 (row 1).
// ---------------------------------------------------------------------------
__global__ void init_k(const uint32_t* __restrict__ emb_raw,
                       int* __restrict__ flag, unsigned* __restrict__ bars) {
    const int t = threadIdx.x;
    for (int k = t; k < NBARU; k += 1024) bars[k] = 0u;
    if (t == 0) {
        uint32_t acc = 0;
        for (int i = 64; i < 128; ++i) acc |= emb_raw[i];
        *flag = (acc == 0u) ? 0 : 1;
    }
}

// ---------------------------------------------------------------------------
// G[c][j]: input-side gate pre-activations per class. j = q*512 + col,
// q in {0:f, 1:i, 2:o, 3:ctilde}; ctilde quarter pre-sigmoided.
// ---------------------------------------------------------------------------
template <bool BF>
__global__ void build_G(const int* __restrict__ flag,
                        const void* __restrict__ emb,
                        const void* __restrict__ Wfx, const void* __restrict__ Wix,
                        const void* __restrict__ Wox, const void* __restrict__ Wcx,
                        const void* __restrict__ bfv, const void* __restrict__ biv,
                        const void* __restrict__ bov, const void* __restrict__ bcv,
                        float* __restrict__ G) {
    if (*flag != (BF ? 1 : 0)) return;
    const int c   = blockIdx.x;
    const int j   = blockIdx.y * 256 + threadIdx.x;
    const int q   = j >> 9;
    const int col = j & 511;
    const void* W  = (q == 0) ? Wfx : (q == 1) ? Wix : (q == 2) ? Wox : Wcx;
    const void* bv = (q == 0) ? bfv : (q == 1) ? biv : (q == 2) ? bov : bcv;
    float acc = ldv<BF>(bv, col);
    for (int i = 0; i < ID; ++i)
        acc += ldv<BF>(emb, c * ID + i) * ldv<BF>(W, i * HD + col);
    if (q == 3) acc = sigf(acc);
    G[c * 2048 + j] = acc;
}

// ---------------------------------------------------------------------------
// Recurrence body. FAST (canary-verified XCD-local group): C exchange via
// plain write-through stores + volatile (sc0) loads at the XCD L2 (~200cyc),
// barrier counter via workgroup-scope RMW (executes at the same L2) +
// volatile poll. SLOW: r13's proven IF path verbatim.
// Epilogue: o-gate dots Woc against C1 = C(T-1) — the reference computes o
// from the PRE-update C at the final step (r15's verified fix).
// ---------------------------------------------------------------------------
template <bool BF, bool FAST>
__device__ void run_rec(
    int t0, int r0, int h0,
    const float (&wf)[16], const float (&wi)[16],
    float* Cs, float2* part2, const int* idx,
    const float* __restrict__ G, const void* __restrict__ Woc,
    float* __restrict__ C0, float* __restrict__ C1, float* __restrict__ Hfb,
    unsigned* cnt)
{
    const int tid   = threadIdx.x;
    const int col   = tid & 31;
    const int chunk = tid >> 5;
    const int erow  = tid >> 7;
    const int eh4   = (tid & 127) * 4;
    const bool isUpd = (tid < COLS * RPG);
    const int uc = tid & 31, ur = tid >> 5;

    float Creg = 0.0f;
    unsigned it = 0;

    for (int t = t0; t < TT; ++t) {
        const float* cur = (t & 1) ? C1 : C0;
        float*       nxt = (t & 1) ? C0 : C1;

        // prefetch G gate operands for the update (overlaps the stage)
        float gf = 0.f, gi = 0.f, sgc = 0.f;
        int cl = 1;
        if (isUpd) {
            cl = idx[ur * TT + t];
            const float* Gr = G + cl * 2048;
            gf  = Gr[h0 + uc];
            gi  = Gr[512 + h0 + uc];
            sgc = Gr[1536 + h0 + uc];
        }

        // stage C(t): 4 consecutive floats of row erow at h'=eh4
        {
            const float* cb = cur + (r0 + erow) * HD + eh4;
            float* cs = Cs + erow * CPAD + eh4;
            if constexpr (FAST) {
                const u64 a = *(volatile const u64*)(cb);
                const u64 b = *(volatile const u64*)(cb + 2);
                cs[0] = __uint_as_float((unsigned)a);
                cs[1] = __uint_as_float((unsigned)(a >> 32));
                cs[2] = __uint_as_float((unsigned)b);
                cs[3] = __uint_as_float((unsigned)(b >> 32));
            } else {
                const float v0 = cld(cb);
                const float v1 = cld(cb + 1);
                const float v2 = cld(cb + 2);
                const float v3 = cld(cb + 3);
                cs[0] = v0; cs[1] = v1; cs[2] = v2; cs[3] = v3;
            }
        }
        __syncthreads();

        // both-gate dot over 16 h' (2-way broadcast LDS reads)
        float accf[RPG], acci[RPG];
        #pragma unroll
        for (int r = 0; r < RPG; ++r) { accf[r] = 0.0f; acci[r] = 0.0f; }
        {
            const int cb4 = chunk * 4;
            #pragma unroll
            for (int j = 0; j < 4; ++j) {
                const float f0 = wf[4*j], f1 = wf[4*j+1], f2 = wf[4*j+2], f3 = wf[4*j+3];
                const float i0 = wi[4*j], i1 = wi[4*j+1], i2 = wi[4*j+2], i3 = wi[4*j+3];
                #pragma unroll
                for (int r = 0; r < RPG; ++r) {
                    const float4 cv = reinterpret_cast<const float4*>(
                        Cs + r * CPAD)[cb4 + j];
                    accf[r] += f0*cv.x + f1*cv.y + f2*cv.z + f3*cv.w;
                    acci[r] += i0*cv.x + i1*cv.y + i2*cv.z + i3*cv.w;
                }
            }
        }
        {
            float2* pp = part2 + tid * PST2;
            #pragma unroll
            for (int r = 0; r < RPG; ++r)
                pp[r] = make_float2(accf[r], acci[r]);
        }
        __syncthreads();

        // update: thread t<256 owns (col = uc, row = ur)
        if (isUpd) {
            float df = 0.f, di = 0.f;
            #pragma unroll
            for (int ch = 0; ch < 32; ++ch) {
                const float2 v = part2[(ch * 32 + uc) * PST2 + ur];
                df += v.x;
                di += v.y;
            }
            float Cn = sgc * sigf(gi + di) + Creg * sigf(gf + df);
            Cn = (cl > 0) ? Cn : 0.0f;
            Creg = Cn;
            float* dst = &nxt[(r0 + ur) * HD + h0 + uc];
            if constexpr (FAST) *dst = Cn;     // write-through -> XCD L2
            else                cst(dst, Cn);
        }

        // group barrier (syncthreads drains the C stores before arrive)
        __syncthreads();
        if (tid == 0) {
            ++it;
            const unsigned tgt = it * GWG;
            if constexpr (FAST) {
                __hip_atomic_fetch_add(cnt, 1u, __ATOMIC_RELAXED,
                                       __HIP_MEMORY_SCOPE_WORKGROUP);
                while (*(volatile const unsigned*)cnt < tgt)
                    ;
            } else {
                __hip_atomic_fetch_add(cnt, 1u, __ATOMIC_RELAXED,
                                       __HIP_MEMORY_SCOPE_AGENT);
                while (__hip_atomic_load(cnt, __ATOMIC_RELAXED,
                                         __HIP_MEMORY_SCOPE_AGENT) < tgt)
                    ;
            }
        }
        __syncthreads();
    }

    // o-gate + h once. o uses C(T-1) = C1 (pre-update at the final step;
    // TT-1 odd -> final step's input buffer is C1, untouched by its update).
    {
        const float* cb = C1 + (r0 + erow) * HD + eh4;
        float* cs = Cs + erow * CPAD + eh4;
        if constexpr (FAST) {
            const u64 a = *(volatile const u64*)(cb);
            const u64 b = *(volatile const u64*)(cb + 2);
            cs[0] = __uint_as_float((unsigned)a);
            cs[1] = __uint_as_float((unsigned)(a >> 32));
            cs[2] = __uint_as_float((unsigned)b);
            cs[3] = __uint_as_float((unsigned)(b >> 32));
        } else {
            const float v0 = cld(cb);
            const float v1 = cld(cb + 1);
            const float v2 = cld(cb + 2);
            const float v3 = cld(cb + 3);
            cs[0] = v0; cs[1] = v1; cs[2] = v2; cs[3] = v3;
        }
        __syncthreads();

        float ao[RPG];
        #pragma unroll
        for (int r = 0; r < RPG; ++r) ao[r] = 0.0f;
        #pragma unroll 4
        for (int k = 0; k < 16; ++k) {
            const int hp = chunk * 16 + k;
            const float wo = ldv<BF>(Woc, hp * HD + h0 + col);
            #pragma unroll
            for (int r = 0; r < RPG; ++r)
                ao[r] += wo * Cs[r * CPAD + hp];
        }
        {
            float2* pp = part2 + tid * PST2;
            #pragma unroll
            for (int r2 = 0; r2 < RPG / 2; ++r2)
                pp[r2] = make_float2(ao[2 * r2], ao[2 * r2 + 1]);
        }
        __syncthreads();
        if (isUpd) {
            float s = 0.f;
            #pragma unroll
            for (int ch = 0; ch < 32; ++ch) {
                const float2 v = part2[(ch * 32 + uc) * PST2 + (ur >> 1)];
                s += (ur & 1) ? v.y : v.x;
            }
            const int cl2 = idx[ur * TT + TT - 1];
            const float o = sigf(G[cl2 * 2048 + 1024 + h0 + uc] + s);
            Hfb[(r0 + ur) * HD + h0 + uc] = tanhf(Creg) * o;
        }
    }
}

// ---------------------------------------------------------------------------
// Batch-split recurrence. Swizzle makes each group's 16 WGs XCD-local IF the
// dispatcher round-robins blk->XCD (blk&7). The fast path engages only after
// (a) all 16 WGs report the same HW_REG_XCC_ID (numeric-encoded getreg
// builtin; garbage just disables), AND (b) a CANARY proves the exact
// plain-store -> volatile-load L2 visibility the fast path relies on:
// prewarm own L1 with the zeroed canary lines, IF-barrier, plain-store
// magics, IF-barrier, volatile read-back. Stale-L1 (volatile==plain),
// stale-IF (volatile==sc0+sc1), or cross-XCD all read non-magic -> proven
// r13 slow path. No hang mode: every preamble barrier is the IF barrier.
// ---------------------------------------------------------------------------
template <bool BF>
__global__ __launch_bounds__(THR, 1) void recur_bs(
    const int* __restrict__ flag, const int* __restrict__ x,
    const float* __restrict__ G,
    const void* __restrict__ Wfc, const void* __restrict__ Wic,
    const void* __restrict__ Woc,
    float* __restrict__ C0, float* __restrict__ C1,
    float* __restrict__ Hfb, unsigned* __restrict__ bars)
{
    if (*flag != (BF ? 1 : 0)) return;

    __shared__ __align__(16) float Cs[RPG * CPAD];     // 16.6 KB
    __shared__ __align__(8)  float2 part2[THR * PST2]; // 73.7 KB
    __shared__ int idx[RPG * TT];                      // 16 KB
    __shared__ int lz[RPG];
    __shared__ int fast_s;

    const int blk   = blockIdx.x;
    const int xcd   = blk & 7;            // round-robin heuristic (perf only)
    const int j     = blk >> 3;           // 0..31
    const int grp   = xcd * 2 + (j >> 4); // 0..15
    const int rank  = j & 15;             // 0..15
    const int r0    = grp * RPG;
    const int h0    = rank * COLS;
    const int tid   = threadIdx.x;
    const int col   = tid & 31;
    const int chunk = tid >> 5;

    unsigned* cntIF1 = bars + grp * 64;
    unsigned* cntIF2 = bars + grp * 64 + 16;
    unsigned* cntL2  = bars + grp * 64 + 32;
    unsigned* xslots = bars + 2048 + grp * 16;
    unsigned* cslots = bars + 4096 + grp * 512;   // rank slot at rank*32

    // ---- stage x rows (4096 ints, flat-contiguous), find group start ----
    #pragma unroll
    for (int k = 0; k < 4; ++k)
        idx[tid + 1024 * k] = x[r0 * TT + tid + 1024 * k];
    if (tid < RPG) lz[tid] = -1;
    __syncthreads();
    if (tid < TT)
        #pragma unroll
        for (int r = 0; r < RPG; ++r)
            if (idx[r * TT + tid] == 0) atomicMax(&lz[r], tid);
    __syncthreads();
    int t0 = TT;
    #pragma unroll
    for (int r = 0; r < RPG; ++r) t0 = min(t0, lz[r] + 1);
    // t0 is group-uniform: every WG computes it from the same 8 rows.

    // ---- 32 pinned register weights: BOTH gates, own col, own 16-h' chunk
    float wf[16], wi[16];
    {
        #pragma unroll
        for (int k = 0; k < 16; ++k) {
            wf[k] = ldv<BF>(Wfc, (chunk * 16 + k) * HD + h0 + col);
            wi[k] = ldv<BF>(Wic, (chunk * 16 + k) * HD + h0 + col);
        }
        #pragma unroll
        for (int k = 0; k < 16; ++k)
            asm volatile("" : "+v"(wf[k]), "+v"(wi[k]));
    }

    // ---- XCD co-residency + canary check ----
    unsigned bi1 = 0;
    unsigned prewarm = 0;
    {
        // hwreg(HW_REG_XCC_ID=20, offset 0, width 32) numeric encoding 63508.
        // If the id is wrong on this chip, values differ or are garbage ->
        // fast simply stays off. No asm, no symbolic names.
        const unsigned xid = __builtin_amdgcn_s_getreg(63508);
        if (tid == 0) cst_u(xslots + rank, (xid & 255u) + 1u);

        // canary prewarm: pull the (zeroed) canary lines into our L1 with
        // PLAIN loads, so a plain-lowered "volatile" later reads stale 0.
        if (tid == 0) {
            unsigned a = 0;
            for (int rr = 0; rr < GWG; ++rr)
                a |= cslots[rr * 32];
            prewarm = a;                     // all 0 from init_k
        }
        gbar_if(cntIF1, &bi1);               // xids published, prewarm done

        if (tid == 0)
            cslots[rank * 32] = 0x5EED0000u + (unsigned)rank;  // plain store
        gbar_if(cntIF1, &bi1);               // magics drained (vmcnt) + visible-if-L2

        if (tid == 0) {
            const unsigned v0 = cld_u(xslots);
            int same = (v0 != 0u);
            for (int rr = 1; rr < GWG; ++rr)
                same &= (cld_u(xslots + rr) == v0);
            int ok = (prewarm == 0u);
            for (int rr = 0; rr < GWG; ++rr)
                ok &= (*(volatile const unsigned*)(cslots + rr * 32)
                       == 0x5EED0000u + (unsigned)rr);
            fast_s = same && ok;
        }
        __syncthreads();
    }
    const bool fast = (fast_s != 0);

    // ---- zero own C slices in both buffers (flavored stores) ----
    if (tid < COLS * RPG) {
        const int c = tid & 31, r = tid >> 5;
        float* p0 = &C0[(r0 + r) * HD + h0 + c];
        float* p1 = &C1[(r0 + r) * HD + h0 + c];
        if (fast) { *p0 = 0.0f; *p1 = 0.0f; }
        else      { cst(p0, 0.0f); cst(p1, 0.0f); }
    }
    gbar_if(cntIF1, &bi1);                   // zeros visible group-wide

    if (fast)
        run_rec<BF, true >(t0, r0, h0, wf, wi, Cs, part2, idx,
                           G, Woc, C0, C1, Hfb, cntL2);
    else
        run_rec<BF, false>(t0, r0, h0, wf, wi, Cs, part2, idx,
                           G, Woc, C0, C1, Hfb, cntIF2);
}

// ---------------------------------------------------------------------------
// Projection + log_softmax, one WG per batch row. (Kernel-boundary release
// makes recur's plain Hfb stores visible here.)
// ---------------------------------------------------------------------------
template <bool BF>
__global__ __launch_bounds__(128) void proj(
    const int* __restrict__ flag, const float* __restrict__ Hfb,
    const void* __restrict__ Wph, const void* __restrict__ bp,
    void* __restrict__ out)
{
    if (*flag != (BF ? 1 : 0)) return;
    __shared__ __align__(16) float hv[HD];
    __shared__ float p_s[NCLS];
    __shared__ float lse_s;
    const int b   = blockIdx.x;
    const int tid = threadIdx.x;

    reinterpret_cast<float4*>(hv)[tid] =
        reinterpret_cast<const float4*>(Hfb + b * HD)[tid];
    __syncthreads();

    if (tid < NCLS) {
        float p = ldv<BF>(bp, tid);
        for (int h = 0; h < HD; ++h)
            p += hv[h] * ldv<BF>(Wph, h * NCLS + tid);
        p_s[tid] = p;
    }
    __syncthreads();
    if (tid == 0) {
        float m = -1e30f;
        for (int n = 0; n < NCLS; ++n) m = fmaxf(m, p_s[n]);
        float sum = 0.0f;
        for (int n = 0; n < NCLS; ++n) sum += expf(p_s[n] - m);
        lse_s = m + logf(sum);
    }
    __syncthreads();
    if (tid < NCLS) {
        const float v = p_s[tid] - lse_s;
        if constexpr (BF) ((bf16*)out)[b * NCLS + tid] = __float2bfloat16(v);
        else              ((float*)out)[b * NCLS + tid] = v;
    }
}

// ---------------------------------------------------------------------------
extern "C" void kernel_launch(void* const* d_in, const int* in_sizes, int n_in,
                              void* d_out, int out_size, void* d_ws, size_t ws_size,
                              hipStream_t stream) {
    const int*  x   = (const int*)d_in[0];
    const void* emb = d_in[1];
    const void* Wfx = d_in[2];
    const void* Wfc = d_in[3];
    const void* bfv = d_in[4];
    const void* Wix = d_in[5];
    const void* Wic = d_in[6];
    const void* biv = d_in[7];
    const void* Wox = d_in[8];
    const void* Woc = d_in[9];
    const void* bov = d_in[10];
    const void* Wcx = d_in[11];
    const void* bcv = d_in[12];
    const void* Wph = d_in[13];
    const void* bp  = d_in[14];

    int*      flag = (int*)((char*)d_ws + WS_FLAG);
    unsigned* bars = (unsigned*)((char*)d_ws + WS_BAR);
    float*    G    = (float*)((char*)d_ws + WS_G);
    float*    C0   = (float*)((char*)d_ws + WS_C0);
    float*    C1   = (float*)((char*)d_ws + WS_C1);
    float*    Hfb  = (float*)((char*)d_ws + WS_HFB);

    init_k<<<1, 1024, 0, stream>>>((const uint32_t*)emb, flag, bars);

    build_G<false><<<dim3(NEMB, 8), 256, 0, stream>>>(flag, emb, Wfx, Wix, Wox, Wcx,
                                                      bfv, biv, bov, bcv, G);
    build_G<true ><<<dim3(NEMB, 8), 256, 0, stream>>>(flag, emb, Wfx, Wix, Wox, Wcx,
                                                      bfv, biv, bov, bcv, G);

    {
        void* args[] = {(void*)&flag, (void*)&x, (void*)&G,
                        (void*)&Wfc, (void*)&Wic, (void*)&Woc,
                        (void*)&C0, (void*)&C1, (void*)&Hfb, (void*)&bars};
        hipLaunchCooperativeKernel((const void*)recur_bs<false>, dim3(NGRP * GWG), dim3(THR),
                                   args, 0, stream);
        hipLaunchCooperativeKernel((const void*)recur_bs<true>, dim3(NGRP * GWG), dim3(THR),
                                   args, 0, stream);
    }

    proj<false><<<BB, 128, 0, stream>>>(flag, Hfb, Wph, bp, d_out);
    proj<true ><<<BB, 128, 0, stream>>>(flag, Hfb, Wph, bp, d_out);
}

// Round 18
// 1663.719 us; speedup vs baseline: 1.5762x; 1.5406x over previous
//
#include <hip/hip_runtime.h>
#include <hip/hip_bf16.h>
#include <stdint.h>

#define HD   512   // hidden dim H
#define ID   128   // input dim I
#define NCLS 100   // num classes
#define TT   512   // sequence length T
#define BB   128   // batch B
#define NEMB 101   // NC + 1 embedding rows
#define NGRP 32    // independent batch groups
#define GWG  8     // workgroups per group (sync clique)
#define RPG  4     // batch rows per group
#define COLS 64    // hidden cols per WG (GWG*COLS == HD)
#define THR  1024  // threads per recurrence WG (16 waves, 4 waves/SIMD)
#define CPAD 520   // LDS C row stride (mult of 4 -> float4-aligned; skews banks)
#define PST  5     // partials slot stride in float2 (4 rows + 1 pad)

// workspace layout (bytes)
#define WS_FLAG 0
#define WS_BAR  4096                   // u32 bars[NGRP*32] (128 B apart)
#define WS_G    65536                  // float G[101][2048]  (808 KB)
#define WS_C0   (1u * 1024 * 1024)     // float C0[128][512]  (256 KB)
#define WS_C1   (WS_C0 + 262144)       // float C1[128][512]  (256 KB)
#define WS_HFB  (WS_C1 + 262144)       // float Hfb[128][512] (256 KB)
#define NBARU   4096                   // u32s to zero

using bf16 = __hip_bfloat16;

__device__ __forceinline__ float b2f(bf16 v) { return __bfloat162float(v); }
__device__ __forceinline__ float sigf(float x) { return 1.0f / (1.0f + expf(-x)); }

// IF-scope (sc1) accessors — proven r6-r17.
__device__ __forceinline__ float cld(const float* p) {
    return __hip_atomic_load(p, __ATOMIC_RELAXED, __HIP_MEMORY_SCOPE_AGENT);
}
__device__ __forceinline__ void cst(float* p, float v) {
    __hip_atomic_store(p, v, __ATOMIC_RELAXED, __HIP_MEMORY_SCOPE_AGENT);
}

template <bool BF>
__device__ __forceinline__ float ldv(const void* p, int i) {
    if constexpr (BF) return b2f(((const bf16*)p)[i]);
    else              return ((const float*)p)[i];
}

// ---------------------------------------------------------------------------
// Group barrier — r13's best-measured flavor (IF RMW + tight poll). The
// leading __syncthreads drains all waves' sc1 C stores before the arrive.
// Measured ranking: RMW-IF 2256 < L2-local 2563 ~ slot 2566 ~ tagged 2622.
// ---------------------------------------------------------------------------
__device__ __forceinline__ void gbarrier(unsigned* cnt, unsigned* iter) {
    __syncthreads();
    if (threadIdx.x == 0) {
        __hip_atomic_fetch_add(cnt, 1u, __ATOMIC_RELAXED, __HIP_MEMORY_SCOPE_AGENT);
        const unsigned tgt = (*iter + 1u) * GWG;
        while (__hip_atomic_load(cnt, __ATOMIC_RELAXED, __HIP_MEMORY_SCOPE_AGENT) < tgt)
            ;
    }
    ++*iter;
    __syncthreads();
}

// ---------------------------------------------------------------------------
// Dtype sniffer + bars zeroing. emb row 0 is exactly 0.0 by construction:
// bytes [256,512) are zero iff f32 (row 0) and nonzero iff bf16 (row 1).
// ---------------------------------------------------------------------------
__global__ void init_k(const uint32_t* __restrict__ emb_raw,
                       int* __restrict__ flag, unsigned* __restrict__ bars) {
    const int t = threadIdx.x;
    for (int k = t; k < NBARU; k += 1024) bars[k] = 0u;
    if (t == 0) {
        uint32_t acc = 0;
        for (int i = 64; i < 128; ++i) acc |= emb_raw[i];
        *flag = (acc == 0u) ? 0 : 1;
    }
}

// ---------------------------------------------------------------------------
// G[c][j]: input-side gate pre-activations per class. j = q*512 + col,
// q in {0:f, 1:i, 2:o, 3:ctilde}; ctilde quarter pre-sigmoided.
// ---------------------------------------------------------------------------
template <bool BF>
__global__ void build_G(const int* __restrict__ flag,
                        const void* __restrict__ emb,
                        const void* __restrict__ Wfx, const void* __restrict__ Wix,
                        const void* __restrict__ Wox, const void* __restrict__ Wcx,
                        const void* __restrict__ bfv, const void* __restrict__ biv,
                        const void* __restrict__ bov, const void* __restrict__ bcv,
                        float* __restrict__ G) {
    if (*flag != (BF ? 1 : 0)) return;
    const int c   = blockIdx.x;
    const int j   = blockIdx.y * 256 + threadIdx.x;
    const int q   = j >> 9;
    const int col = j & 511;
    const void* W  = (q == 0) ? Wfx : (q == 1) ? Wix : (q == 2) ? Wox : Wcx;
    const void* bv = (q == 0) ? bfv : (q == 1) ? biv : (q == 2) ? bov : bcv;
    float acc = ldv<BF>(bv, col);
    for (int i = 0; i < ID; ++i)
        acc += ldv<BF>(emb, c * ID + i) * ldv<BF>(W, i * HD + col);
    if (q == 3) acc = sigf(acc);
    G[c * 2048 + j] = acc;
}

// ---------------------------------------------------------------------------
// Batch-split recurrence, 32 groups x 8 WGs x 64 cols. Thread t:
//   cp = t&31 -> own cols h0+cp and h0+cp+32; chunk = t>>5 -> 16 h';
//   ALL 4 rows. 64 pinned weight regs (2 cols x 2 gates x 16 h') re-pinned
//   INSIDE the t-loop so the allocator cannot evict them (r7/r8/r10 all
//   spilled pre-loop-pinned arrays; the in-loop pin makes residency the
//   only cheap option). Each C float4 LDS read now feeds 16 FMAs (was 8):
//   dot reads drop 512 -> 256 b128/CU/step — the measured LDS-pipe floor.
//   Per read instruction: lanes 0..31 chunk A, 32..63 chunk B -> 2-way
//   broadcast (free, m136).
// Per step: [prefetch G] stage C(t) (2 sc1 loads/thread) -> sync -> dot
// (16 b128 reads, 256 FMA/thread) -> float2 partials -> sync -> 256 update
// threads (gates, own C in Creg, sc1-store) -> 8-way IF barrier.
// Epilogue: o-gate dots Woc against C1 = C(T-1) (pre-update C at the final
// step — r15's verified fix; TT-1 odd -> final input buffer is C1).
// ---------------------------------------------------------------------------
template <bool BF>
__global__ __launch_bounds__(THR, 1) void recur_bs(
    const int* __restrict__ flag, const int* __restrict__ x,
    const float* __restrict__ G,
    const void* __restrict__ Wfc, const void* __restrict__ Wic,
    const void* __restrict__ Woc,
    float* __restrict__ C0, float* __restrict__ C1,
    float* __restrict__ Hfb, unsigned* __restrict__ bars)
{
    if (*flag != (BF ? 1 : 0)) return;

    __shared__ __align__(16) float Cs[RPG * CPAD];        // 8.3 KB
    __shared__ __align__(8)  float2 part2[2048 * PST];    // 80 KB
    __shared__ int idx[RPG * TT];                         // 8 KB
    __shared__ int lz[RPG];

    const int blk   = blockIdx.x;
    const int grp   = blk >> 3;           // 0..31
    const int rank  = blk & 7;            // 0..7
    const int r0    = grp * RPG;
    const int h0    = rank * COLS;
    const int tid   = threadIdx.x;
    const int cp    = tid & 31;           // col pair: cols cp, cp+32
    const int chunk = tid >> 5;           // 0..31 (16 h' each)
    unsigned* bar = bars + grp * 32;      // 128 B apart

    // ---- stage x rows (2048 ints, flat-contiguous), find group start ----
    idx[tid]        = x[r0 * TT + tid];
    idx[tid + 1024] = x[r0 * TT + tid + 1024];
    if (tid < RPG) lz[tid] = -1;
    __syncthreads();
    if (tid < TT)
        #pragma unroll
        for (int r = 0; r < RPG; ++r)
            if (idx[r * TT + tid] == 0) atomicMax(&lz[r], tid);
    __syncthreads();
    int t0 = TT;
    #pragma unroll
    for (int r = 0; r < RPG; ++r) t0 = min(t0, lz[r] + 1);
    // t0 is group-uniform: every WG computes it from the same 4 rows.

    // ---- 64 pinned register weights: 2 cols x 2 gates x own 16-h' chunk --
    float wfA[16], wfB[16], wiA[16], wiB[16];
    #pragma unroll
    for (int k = 0; k < 16; ++k) {
        const int hp = chunk * 16 + k;
        wfA[k] = ldv<BF>(Wfc, hp * HD + h0 + cp);
        wfB[k] = ldv<BF>(Wfc, hp * HD + h0 + cp + 32);
        wiA[k] = ldv<BF>(Wic, hp * HD + h0 + cp);
        wiB[k] = ldv<BF>(Wic, hp * HD + h0 + cp + 32);
    }
    #pragma unroll
    for (int k = 0; k < 16; ++k)
        asm volatile("" : "+v"(wfA[k]), "+v"(wfB[k]), "+v"(wiA[k]), "+v"(wiB[k]));

    // ---- zero own C slices in both buffers (coherent stores) ----
    if (tid < COLS * RPG) {
        const int c = tid & 63, r = tid >> 6;
        cst(&C0[(r0 + r) * HD + h0 + c], 0.0f);
        cst(&C1[(r0 + r) * HD + h0 + c], 0.0f);
    }
    unsigned bi = 0;
    gbarrier(bar, &bi);                   // zeros visible group-wide

    float Creg = 0.0f;                    // update threads' own C element
    const int erow = tid >> 9;            // stage: row 0..1 (and +2)
    const int ehp  = tid & 511;           // stage: h'
    const bool isUpd = (tid < COLS * RPG);
    const int uc = tid & 63, ur = tid >> 6;   // update thread's (col, row)

    for (int t = t0; t < TT; ++t) {
        // re-pin the weights every iteration: forces them to stay VGPR-
        // resident through the loop body (the pre-loop pin alone was not
        // enough in r7/r8/r10 — allocator spilled after the asm point).
        #pragma unroll
        for (int k = 0; k < 16; ++k)
            asm volatile("" : "+v"(wfA[k]), "+v"(wfB[k]), "+v"(wiA[k]), "+v"(wiB[k]));

        const float* cur = (t & 1) ? C1 : C0;
        float*       nxt = (t & 1) ? C0 : C1;

        // ---- prefetch G gate operands for the update (overlaps the stage)
        float gf = 0.f, gi = 0.f, sgc = 0.f;
        int cl = 1;
        if (isUpd) {
            cl = idx[ur * TT + t];
            const float* Gr = G + cl * 2048;
            gf  = Gr[h0 + uc];
            gi  = Gr[512 + h0 + uc];
            sgc = Gr[1536 + h0 + uc];
        }

        // ---- stage C(t): rows erow and erow+2 at h'=ehp ----
        {
            const float v0 = cld(cur + (r0 + erow) * HD + ehp);
            const float v1 = cld(cur + (r0 + erow + 2) * HD + ehp);
            Cs[erow * CPAD + ehp]       = v0;
            Cs[(erow + 2) * CPAD + ehp] = v1;
        }
        __syncthreads();

        // ---- 2-col dot over 16 h', all 4 rows (2-way broadcast reads) ----
        float fA[RPG], fB[RPG], iA[RPG], iB[RPG];
        #pragma unroll
        for (int r = 0; r < RPG; ++r) { fA[r] = 0.f; fB[r] = 0.f; iA[r] = 0.f; iB[r] = 0.f; }
        {
            const int cb4 = chunk * 4;    // float4 index of chunk base
            #pragma unroll
            for (int j = 0; j < 4; ++j) {
                const float a0 = wfA[4*j], a1 = wfA[4*j+1], a2 = wfA[4*j+2], a3 = wfA[4*j+3];
                const float b0 = wfB[4*j], b1 = wfB[4*j+1], b2 = wfB[4*j+2], b3 = wfB[4*j+3];
                const float c0 = wiA[4*j], c1 = wiA[4*j+1], c2 = wiA[4*j+2], c3 = wiA[4*j+3];
                const float d0 = wiB[4*j], d1 = wiB[4*j+1], d2 = wiB[4*j+2], d3 = wiB[4*j+3];
                #pragma unroll
                for (int r = 0; r < RPG; ++r) {
                    const float4 cv = reinterpret_cast<const float4*>(
                        Cs + r * CPAD)[cb4 + j];
                    fA[r] += a0*cv.x + a1*cv.y + a2*cv.z + a3*cv.w;
                    fB[r] += b0*cv.x + b1*cv.y + b2*cv.z + b3*cv.w;
                    iA[r] += c0*cv.x + c1*cv.y + c2*cv.z + c3*cv.w;
                    iB[r] += d0*cv.x + d1*cv.y + d2*cv.z + d3*cv.w;
                }
            }
        }
        {
            float2* ppA = part2 + (chunk * 64 + cp)      * PST;
            float2* ppB = part2 + (chunk * 64 + cp + 32) * PST;
            #pragma unroll
            for (int r = 0; r < RPG; ++r) {
                ppA[r] = make_float2(fA[r], iA[r]);
                ppB[r] = make_float2(fB[r], iB[r]);
            }
        }
        __syncthreads();

        // ---- update: thread t<256 owns (col = uc, row = ur) ----
        if (isUpd) {
            float df = 0.f, di = 0.f;
            #pragma unroll
            for (int ch = 0; ch < 32; ++ch) {
                const float2 v = part2[(ch * 64 + uc) * PST + ur];
                df += v.x;
                di += v.y;
            }
            float Cn = sgc * sigf(gi + di) + Creg * sigf(gf + df);
            Cn = (cl > 0) ? Cn : 0.0f;
            Creg = Cn;
            cst(&nxt[(r0 + ur) * HD + h0 + uc], Cn);
        }
        gbarrier(bar, &bi);
    }

    // ---- o-gate + h once. o uses C(T-1) = C1 (pre-update at final step) --
    {
        const float v0 = cld(C1 + (r0 + erow) * HD + ehp);
        const float v1 = cld(C1 + (r0 + erow + 2) * HD + ehp);
        Cs[erow * CPAD + ehp]       = v0;
        Cs[(erow + 2) * CPAD + ehp] = v1;
        __syncthreads();

        // thread = (oc = t&63 col, och = t>>6: 16 chunks x 32 h')
        const int oc = tid & 63, och = tid >> 6;
        float ao[RPG];
        #pragma unroll
        for (int r = 0; r < RPG; ++r) ao[r] = 0.0f;
        #pragma unroll 4
        for (int k = 0; k < 32; ++k) {
            const int hp = och * 32 + k;
            const float wo = ldv<BF>(Woc, hp * HD + h0 + oc);
            #pragma unroll
            for (int r = 0; r < RPG; ++r)
                ao[r] += wo * Cs[r * CPAD + hp];
        }
        {
            float2* pp = part2 + (och * 64 + oc) * PST;
            #pragma unroll
            for (int r2 = 0; r2 < RPG / 2; ++r2)
                pp[r2] = make_float2(ao[2 * r2], ao[2 * r2 + 1]);
        }
        __syncthreads();
        if (isUpd) {
            float s = 0.f;
            #pragma unroll
            for (int ch = 0; ch < 16; ++ch) {
                const float2 v = part2[(ch * 64 + uc) * PST + (ur >> 1)];
                s += (ur & 1) ? v.y : v.x;
            }
            const int cl2 = idx[ur * TT + TT - 1];
            const float o = sigf(G[cl2 * 2048 + 1024 + h0 + uc] + s);
            Hfb[(r0 + ur) * HD + h0 + uc] = tanhf(Creg) * o;
        }
    }
}

// ---------------------------------------------------------------------------
// Projection + log_softmax, one WG per batch row.
// ---------------------------------------------------------------------------
template <bool BF>
__global__ __launch_bounds__(128) void proj(
    const int* __restrict__ flag, const float* __restrict__ Hfb,
    const void* __restrict__ Wph, const void* __restrict__ bp,
    void* __restrict__ out)
{
    if (*flag != (BF ? 1 : 0)) return;
    __shared__ __align__(16) float hv[HD];
    __shared__ float p_s[NCLS];
    __shared__ float lse_s;
    const int b   = blockIdx.x;
    const int tid = threadIdx.x;

    reinterpret_cast<float4*>(hv)[tid] =
        reinterpret_cast<const float4*>(Hfb + b * HD)[tid];
    __syncthreads();

    if (tid < NCLS) {
        float p = ldv<BF>(bp, tid);
        for (int h = 0; h < HD; ++h)
            p += hv[h] * ldv<BF>(Wph, h * NCLS + tid);
        p_s[tid] = p;
    }
    __syncthreads();
    if (tid == 0) {
        float m = -1e30f;
        for (int n = 0; n < NCLS; ++n) m = fmaxf(m, p_s[n]);
        float sum = 0.0f;
        for (int n = 0; n < NCLS; ++n) sum += expf(p_s[n] - m);
        lse_s = m + logf(sum);
    }
    __syncthreads();
    if (tid < NCLS) {
        const float v = p_s[tid] - lse_s;
        if constexpr (BF) ((bf16*)out)[b * NCLS + tid] = __float2bfloat16(v);
        else              ((float*)out)[b * NCLS + tid] = v;
    }
}

// ---------------------------------------------------------------------------
extern "C" void kernel_launch(void* const* d_in, const int* in_sizes, int n_in,
                              void* d_out, int out_size, void* d_ws, size_t ws_size,
                              hipStream_t stream) {
    const int*  x   = (const int*)d_in[0];
    const void* emb = d_in[1];
    const void* Wfx = d_in[2];
    const void* Wfc = d_in[3];
    const void* bfv = d_in[4];
    const void* Wix = d_in[5];
    const void* Wic = d_in[6];
    const void* biv = d_in[7];
    const void* Wox = d_in[8];
    const void* Woc = d_in[9];
    const void* bov = d_in[10];
    const void* Wcx = d_in[11];
    const void* bcv = d_in[12];
    const void* Wph = d_in[13];
    const void* bp  = d_in[14];

    int*      flag = (int*)((char*)d_ws + WS_FLAG);
    unsigned* bars = (unsigned*)((char*)d_ws + WS_BAR);
    float*    G    = (float*)((char*)d_ws + WS_G);
    float*    C0   = (float*)((char*)d_ws + WS_C0);
    float*    C1   = (float*)((char*)d_ws + WS_C1);
    float*    Hfb  = (float*)((char*)d_ws + WS_HFB);

    init_k<<<1, 1024, 0, stream>>>((const uint32_t*)emb, flag, bars);

    build_G<false><<<dim3(NEMB, 8), 256, 0, stream>>>(flag, emb, Wfx, Wix, Wox, Wcx,
                                                      bfv, biv, bov, bcv, G);
    build_G<true ><<<dim3(NEMB, 8), 256, 0, stream>>>(flag, emb, Wfx, Wix, Wox, Wcx,
                                                      bfv, biv, bov, bcv, G);

    {
        void* args[] = {(void*)&flag, (void*)&x, (void*)&G,
                        (void*)&Wfc, (void*)&Wic, (void*)&Woc,
                        (void*)&C0, (void*)&C1, (void*)&Hfb, (void*)&bars};
        hipLaunchCooperativeKernel((const void*)recur_bs<false>, dim3(NGRP * GWG), dim3(THR),
                                   args, 0, stream);
        hipLaunchCooperativeKernel((const void*)recur_bs<true>, dim3(NGRP * GWG), dim3(THR),
                                   args, 0, stream);
    }

    proj<false><<<BB, 128, 0, stream>>>(flag, Hfb, Wph, bp, d_out);
    proj<true ><<<BB, 128, 0, stream>>>(flag, Hfb, Wph, bp, d_out);
}